// Round 2
// baseline (46.196 us; speedup 1.0000x reference)
//
#include <hip/hip_runtime.h>

// Post_process_deconv: out = depth + b + sum_k w[k] * (weight[k] - mean_k(weight)) *
//                           bilinear(depth, y - 1 + kh + dy_k, x - 1 + kw + dx_k)
// Shapes: depth [B,1,H,W], weight [B,9,H,W], offset [B,18,H,W], w [1,1,3,3], b [1]
// B=2, H=352, W=1216, K=3, pad=1. All fp32.
//
// 4 pixels per thread (W % 4 == 0 so a group never crosses a row), float4
// plane loads, validity folded into bilinear weights, and the identity
//   sum_k wk*(wv-wmean)*s = sum_k wk*wv*s - wmean * sum_k wk*s
// so wv[9] need not stay live across the k-loop (register pressure control).

#define KK 3
#define K2 9
#define PAD 1
#define BB 2
#define HH 352
#define WW 1216
#define NPX 4

__global__ __launch_bounds__(256) void ppd_kernel(
    const float* __restrict__ depth,   // [B, H*W]
    const float* __restrict__ weight,  // [B, 9, H*W]
    const float* __restrict__ offset,  // [B, 18, H*W]
    const float* __restrict__ wk,      // [9]
    const float* __restrict__ bias,    // [1]
    float* __restrict__ out)           // [B, H*W]
{
    constexpr int HW  = HH * WW;
    constexpr int HW4 = HW / 4;
    constexpr int total_threads = BB * HW / NPX;

    const int tid = blockIdx.x * blockDim.x + threadIdx.x;
    if (tid >= total_threads) return;

    const int pix0 = tid * NPX;
    const int b  = pix0 / HW;           // const divisor -> magic mul
    const int hw = pix0 - b * HW;
    const int y  = hw / WW;
    const int x  = hw - y * WW;         // multiple of 4

    const float*  dimg = depth + (size_t)b * HW;
    const float4* wgt4 = reinterpret_cast<const float4*>(weight + (size_t)b * (K2 * HW) + hw);
    const float4* off4 = reinterpret_cast<const float4*>(offset + (size_t)b * (2 * K2 * HW) + hw);

    float A[NPX]  = {0.f, 0.f, 0.f, 0.f};  // sum_k wk*wv*s
    float S[NPX]  = {0.f, 0.f, 0.f, 0.f};  // sum_k wk*s
    float ws[NPX] = {0.f, 0.f, 0.f, 0.f};  // sum_k wv

#pragma unroll
    for (int k = 0; k < K2; ++k) {
        const int kh = k / KK;
        const int kw = k - kh * KK;
        const float wkk = wk[k];                       // uniform (s_load)

        const float4 wv = wgt4[(size_t)k * HW4];
        const float4 dy = off4[(size_t)(2 * k) * HW4];
        const float4 dx = off4[(size_t)(2 * k + 1) * HW4];

        const float wvv[NPX] = {wv.x, wv.y, wv.z, wv.w};
        const float dyv[NPX] = {dy.x, dy.y, dy.z, dy.w};
        const float dxv[NPX] = {dx.x, dx.y, dx.z, dx.w};

#pragma unroll
        for (int j = 0; j < NPX; ++j) {
            const float py = (float)(y - PAD + kh) + dyv[j];
            const float px = (float)(x + j - PAD + kw) + dxv[j];

            const float y0f = floorf(py);
            const float x0f = floorf(px);
            const float ly = py - y0f;
            const float lx = px - x0f;
            const int y0 = (int)y0f;
            const int x0 = (int)x0f;

            // validity folded into the bilinear weights
            const float wy0 = ((unsigned)y0       < (unsigned)HH) ? (1.f - ly) : 0.f;
            const float wy1 = ((unsigned)(y0 + 1) < (unsigned)HH) ? ly         : 0.f;
            const float wx0 = ((unsigned)x0       < (unsigned)WW) ? (1.f - lx) : 0.f;
            const float wx1 = ((unsigned)(x0 + 1) < (unsigned)WW) ? lx         : 0.f;

            const int y0c = min(max(y0, 0), HH - 1);
            const int y1c = min(max(y0 + 1, 0), HH - 1);
            const int x0c = min(max(x0, 0), WW - 1);
            const int x1c = min(max(x0 + 1, 0), WW - 1);

            const float* r0 = dimg + y0c * WW;
            const float* r1 = dimg + y1c * WW;

            const float s = wy0 * (wx0 * r0[x0c] + wx1 * r0[x1c])
                          + wy1 * (wx0 * r1[x0c] + wx1 * r1[x1c]);

            const float t = wkk * s;
            A[j]  = fmaf(t, wvv[j], A[j]);
            S[j] += t;
            ws[j] += wvv[j];
        }
    }

    const float bb = bias[0];
    const float4 d4 = *reinterpret_cast<const float4*>(dimg + hw);
    const float dv[NPX] = {d4.x, d4.y, d4.z, d4.w};

    float4 o;
    float ov[NPX];
#pragma unroll
    for (int j = 0; j < NPX; ++j) {
        const float wmean = ws[j] * (1.0f / 9.0f);
        ov[j] = fmaf(-wmean, S[j], A[j]) + bb + dv[j];
    }
    o.x = ov[0]; o.y = ov[1]; o.z = ov[2]; o.w = ov[3];
    *reinterpret_cast<float4*>(out + (size_t)b * HW + hw) = o;
}

extern "C" void kernel_launch(void* const* d_in, const int* in_sizes, int n_in,
                              void* d_out, int out_size, void* d_ws, size_t ws_size,
                              hipStream_t stream) {
    const float* depth  = (const float*)d_in[0];
    const float* weight = (const float*)d_in[1];
    const float* offset = (const float*)d_in[2];
    const float* wk     = (const float*)d_in[3];
    const float* bias   = (const float*)d_in[4];
    float* out = (float*)d_out;

    constexpr int total_threads = BB * HH * WW / NPX;
    const int block = 256;
    const int grid = (total_threads + block - 1) / block;
    ppd_kernel<<<grid, block, 0, stream>>>(depth, weight, offset, wk, bias, out);
}

// Round 3
// 36.639 us; speedup vs baseline: 1.2609x; 1.2609x over previous
//
#include <hip/hip_runtime.h>

// Post_process_deconv: out = depth + b + sum_k w[k] * (weight[k] - mean_k(weight)) *
//                           bilinear(depth, y - 1 + kh + dy_k, x - 1 + kw + dx_k)
// Shapes: depth [B,1,H,W], weight [B,9,H,W], offset [B,18,H,W], w [1,1,3,3], b [1]
// B=2, H=352, W=1216, K=3, pad=1. All fp32.
//
// 1 px/thread (best occupancy: 3344 blocks = 13/CU). Key change vs round 1:
// ALL 27 streaming plane loads (9 weight + 18 offset) + residual depth are
// explicitly hoisted into registers before any consumer, so the wave issues
// ~28 outstanding HBM/L3 loads and pays the stream latency ONCE instead of
// ~9 dependent times. The 36 depth gathers then pipeline against a ~5 KB
// L1-resident working set.

#define KK 3
#define K2 9
#define PAD 1
#define BB 2
#define HH 352
#define WW 1216

__global__ __launch_bounds__(256) void ppd_kernel(
    const float* __restrict__ depth,   // [B, H*W]
    const float* __restrict__ weight,  // [B, 9, H*W]
    const float* __restrict__ offset,  // [B, 18, H*W]
    const float* __restrict__ wk,      // [9]
    const float* __restrict__ bias,    // [1]
    float* __restrict__ out)           // [B, H*W]
{
    constexpr int HW = HH * WW;
    constexpr int total = BB * HW;
    const int idx = blockIdx.x * blockDim.x + threadIdx.x;
    if (idx >= total) return;

    const int b  = idx / HW;            // const divisor -> magic mul
    const int hw = idx - b * HW;
    const int y  = hw / WW;
    const int x  = hw - y * WW;

    const float* dimg = depth  + (size_t)b * HW;
    const float* wgt  = weight + (size_t)b * (K2 * HW) + hw;
    const float* off  = offset + (size_t)b * (2 * K2 * HW) + hw;

    // ---- Phase A: issue ALL streaming loads up front (28 outstanding) ----
    float wv[K2], dyv[K2], dxv[K2];
#pragma unroll
    for (int k = 0; k < K2; ++k) wv[k] = wgt[k * HW];
#pragma unroll
    for (int k = 0; k < K2; ++k) {
        dyv[k] = off[(2 * k)     * HW];
        dxv[k] = off[(2 * k + 1) * HW];
    }
    const float dres = dimg[hw];        // residual

    // ---- Phase B: mean + gathers + accumulate ----
    float wsum = 0.f;
#pragma unroll
    for (int k = 0; k < K2; ++k) wsum += wv[k];
    const float wmean = wsum * (1.0f / 9.0f);

    float acc = 0.f;
#pragma unroll
    for (int k = 0; k < K2; ++k) {
        const int kh = k / KK;
        const int kw = k - kh * KK;
        const float py = (float)(y - PAD + kh) + dyv[k];
        const float px = (float)(x - PAD + kw) + dxv[k];

        const float y0f = floorf(py);
        const float x0f = floorf(px);
        const float ly = py - y0f;
        const float lx = px - x0f;
        const int y0 = (int)y0f;
        const int x0 = (int)x0f;

        // validity folded into bilinear weights (zero-outside semantics)
        const float wy0 = ((unsigned)y0       < (unsigned)HH) ? (1.f - ly) : 0.f;
        const float wy1 = ((unsigned)(y0 + 1) < (unsigned)HH) ? ly         : 0.f;
        const float wx0 = ((unsigned)x0       < (unsigned)WW) ? (1.f - lx) : 0.f;
        const float wx1 = ((unsigned)(x0 + 1) < (unsigned)WW) ? lx         : 0.f;

        const int y0c = min(max(y0, 0), HH - 1);
        const int y1c = min(max(y0 + 1, 0), HH - 1);
        const int x0c = min(max(x0, 0), WW - 1);
        const int x1c = min(max(x0 + 1, 0), WW - 1);

        const float* r0 = dimg + y0c * WW;
        const float* r1 = dimg + y1c * WW;

        const float v00 = r0[x0c];
        const float v01 = r0[x1c];
        const float v10 = r1[x0c];
        const float v11 = r1[x1c];

        const float s = wy0 * (wx0 * v00 + wx1 * v01)
                      + wy1 * (wx0 * v10 + wx1 * v11);

        acc = fmaf(wk[k] * (wv[k] - wmean), s, acc);
    }

    out[idx] = acc + bias[0] + dres;
}

extern "C" void kernel_launch(void* const* d_in, const int* in_sizes, int n_in,
                              void* d_out, int out_size, void* d_ws, size_t ws_size,
                              hipStream_t stream) {
    const float* depth  = (const float*)d_in[0];
    const float* weight = (const float*)d_in[1];
    const float* offset = (const float*)d_in[2];
    const float* wk     = (const float*)d_in[3];
    const float* bias   = (const float*)d_in[4];
    float* out = (float*)d_out;

    constexpr int total = BB * HH * WW;
    const int block = 256;
    const int grid = (total + block - 1) / block;
    ppd_kernel<<<grid, block, 0, stream>>>(depth, weight, offset, wk, bias, out);
}

// Round 4
// 27.135 us; speedup vs baseline: 1.7025x; 1.3503x over previous
//
#include <hip/hip_runtime.h>

// Post_process_deconv: out = depth + b + sum_k w[k] * (weight[k] - mean_k(weight)) *
//                           bilinear(depth, y - 1 + kh + dy_k, x - 1 + kw + dx_k)
// Shapes: depth [B,1,H,W], weight [B,9,H,W], offset [B,18,H,W], w [1,1,3,3], b [1]
// B=2, H=352, W=1216, K=3, pad=1. All fp32.
//
// Round 4: the kernel is gather-request-throughput bound (VALU 21%, HBM 18%,
// occupancy fine -> MemUnit). Halve gather traffic: per tap, load each row's
// (x0,x0+1) pair as ONE unaligned float2 (global_load_dwordx2, 4B-aligned ok
// on gfx950) at xb = clamp(x0,0,W-2), then fix up clamp cases with cndmask
// selects. 36 scalar gathers -> 18 dwordx2 gathers per pixel.

#define KK 3
#define K2 9
#define PAD 1
#define BB 2
#define HH 352
#define WW 1216

__global__ __launch_bounds__(256) void ppd_kernel(
    const float* __restrict__ depth,   // [B, H*W]
    const float* __restrict__ weight,  // [B, 9, H*W]
    const float* __restrict__ offset,  // [B, 18, H*W]
    const float* __restrict__ wk,      // [9]
    const float* __restrict__ bias,    // [1]
    float* __restrict__ out)           // [B, H*W]
{
    constexpr int HW = HH * WW;
    constexpr int total = BB * HW;
    const int idx = blockIdx.x * blockDim.x + threadIdx.x;
    if (idx >= total) return;

    const int b  = idx / HW;            // const divisor -> magic mul
    const int hw = idx - b * HW;
    const int y  = hw / WW;
    const int x  = hw - y * WW;

    const float* dimg = depth  + (size_t)b * HW;
    const float* wgt  = weight + (size_t)b * (K2 * HW) + hw;
    const float* off  = offset + (size_t)b * (2 * K2 * HW) + hw;

    // Streaming plane loads (coalesced, compiler keeps them in flight).
    float wv[K2], dyv[K2], dxv[K2];
#pragma unroll
    for (int k = 0; k < K2; ++k) wv[k] = wgt[k * HW];
#pragma unroll
    for (int k = 0; k < K2; ++k) {
        dyv[k] = off[(2 * k)     * HW];
        dxv[k] = off[(2 * k + 1) * HW];
    }
    const float dres = dimg[hw];        // residual

    float wsum = 0.f;
#pragma unroll
    for (int k = 0; k < K2; ++k) wsum += wv[k];
    const float wmean = wsum * (1.0f / 9.0f);

    float acc = 0.f;
#pragma unroll
    for (int k = 0; k < K2; ++k) {
        const int kh = k / KK;
        const int kw = k - kh * KK;
        const float py = (float)(y - PAD + kh) + dyv[k];
        const float px = (float)(x - PAD + kw) + dxv[k];

        const float y0f = floorf(py);
        const float x0f = floorf(px);
        const float ly = py - y0f;
        const float lx = px - x0f;
        const int y0 = (int)y0f;
        const int x0 = (int)x0f;

        // validity folded into bilinear weights (zero-outside semantics)
        const float wy0 = ((unsigned)y0       < (unsigned)HH) ? (1.f - ly) : 0.f;
        const float wy1 = ((unsigned)(y0 + 1) < (unsigned)HH) ? ly         : 0.f;
        const float wx0 = ((unsigned)x0       < (unsigned)WW) ? (1.f - lx) : 0.f;
        const float wx1 = ((unsigned)(x0 + 1) < (unsigned)WW) ? lx         : 0.f;

        const int y0c = min(max(y0, 0), HH - 1);
        const int y1c = min(max(y0 + 1, 0), HH - 1);
        // Base for the row-pair load; x0c, x1c are provably in {xb, xb+1}.
        const int xb  = min(max(x0, 0), WW - 2);
        const int x0c = min(max(x0, 0), WW - 1);
        const int x1c = min(max(x0 + 1, 0), WW - 1);

        const float* r0 = dimg + y0c * WW + xb;
        const float* r1 = dimg + y1c * WW + xb;

        // Unaligned (4B-aligned) 8-byte gathers: one per row instead of two.
        float2 p0, p1;
        __builtin_memcpy(&p0, r0, 8);
        __builtin_memcpy(&p1, r1, 8);

        const bool lo0 = (x0c == xb);
        const bool lo1 = (x1c == xb);
        const float v00 = lo0 ? p0.x : p0.y;
        const float v01 = lo1 ? p0.x : p0.y;
        const float v10 = lo0 ? p1.x : p1.y;
        const float v11 = lo1 ? p1.x : p1.y;

        const float s = wy0 * (wx0 * v00 + wx1 * v01)
                      + wy1 * (wx0 * v10 + wx1 * v11);

        acc = fmaf(wk[k] * (wv[k] - wmean), s, acc);
    }

    out[idx] = acc + bias[0] + dres;
}

extern "C" void kernel_launch(void* const* d_in, const int* in_sizes, int n_in,
                              void* d_out, int out_size, void* d_ws, size_t ws_size,
                              hipStream_t stream) {
    const float* depth  = (const float*)d_in[0];
    const float* weight = (const float*)d_in[1];
    const float* offset = (const float*)d_in[2];
    const float* wk     = (const float*)d_in[3];
    const float* bias   = (const float*)d_in[4];
    float* out = (float*)d_out;

    constexpr int total = BB * HH * WW;
    const int block = 256;
    const int grid = (total + block - 1) / block;
    ppd_kernel<<<grid, block, 0, stream>>>(depth, weight, offset, wk, bias, out);
}